// Round 8
// baseline (12.485 us; speedup 1.0000x reference)
//
#include <hip/hip_runtime.h>

#define BATCH 8192
#define FEAT  512
#define NBLK1 1024   // 4 waves/block, 2 rows/wave -> 8192 rows; 16 waves in flight/CU... full grid
#define NPART NBLK1  // one partial per block (4 KB)

__global__ __launch_bounds__(256) void center_loss_partial(
    const float* __restrict__ features,
    const int*   __restrict__ labels,
    const float* __restrict__ centers,
    float*       __restrict__ partials)
{
    const int lane  = threadIdx.x & 63;
    const int wave  = threadIdx.x >> 6;           // 0..3
    const int gwave = blockIdx.x * 4 + wave;      // 0..4095
    const int row0  = gwave * 2;
    const int row1  = row0 + 1;

    // wave-uniform labels first; the 8 vector loads below overlap their latency
    const int l0 = labels[row0];
    const int l1 = labels[row1];
    const float4* f0 = reinterpret_cast<const float4*>(features + (size_t)row0 * FEAT);
    const float4* f1 = reinterpret_cast<const float4*>(features + (size_t)row1 * FEAT);
    const float4* c0 = reinterpret_cast<const float4*>(centers  + (size_t)l0  * FEAT);
    const float4* c1 = reinterpret_cast<const float4*>(centers  + (size_t)l1  * FEAT);

    // 8 outstanding 1KB coalesced loads per wave (deep MLP)
    float4 a0 = f0[lane];
    float4 a1 = f0[lane + 64];
    float4 a2 = f1[lane];
    float4 a3 = f1[lane + 64];
    float4 b0 = c0[lane];
    float4 b1 = c0[lane + 64];
    float4 b2 = c1[lane];
    float4 b3 = c1[lane + 64];

    float acc, d;
    d = a0.x - b0.x; acc  = d * d;
    d = a0.y - b0.y; acc += d * d;
    d = a0.z - b0.z; acc += d * d;
    d = a0.w - b0.w; acc += d * d;
    d = a1.x - b1.x; acc += d * d;
    d = a1.y - b1.y; acc += d * d;
    d = a1.z - b1.z; acc += d * d;
    d = a1.w - b1.w; acc += d * d;
    d = a2.x - b2.x; acc += d * d;
    d = a2.y - b2.y; acc += d * d;
    d = a2.z - b2.z; acc += d * d;
    d = a2.w - b2.w; acc += d * d;
    d = a3.x - b3.x; acc += d * d;
    d = a3.y - b3.y; acc += d * d;
    d = a3.z - b3.z; acc += d * d;
    d = a3.w - b3.w; acc += d * d;

    #pragma unroll
    for (int off = 32; off > 0; off >>= 1)
        acc += __shfl_down(acc, off, 64);

    __shared__ float smem[4];
    if (lane == 0) smem[wave] = acc;
    __syncthreads();
    if (threadIdx.x == 0)
        partials[blockIdx.x] = smem[0] + smem[1] + smem[2] + smem[3];
}

__global__ __launch_bounds__(256) void center_loss_reduce(
    const float* __restrict__ partials,
    float*       __restrict__ out)
{
    // 1024 partials = 256 float4: exactly one float4 per thread, one round trip
    const float4* p = reinterpret_cast<const float4*>(partials);
    float4 a = p[threadIdx.x];
    float s = (a.x + a.y) + (a.z + a.w);

    #pragma unroll
    for (int off = 32; off > 0; off >>= 1)
        s += __shfl_down(s, off, 64);

    __shared__ float smem[4];
    const int lane = threadIdx.x & 63;
    const int wave = threadIdx.x >> 6;
    if (lane == 0) smem[wave] = s;
    __syncthreads();
    if (threadIdx.x == 0)
        out[0] = (smem[0] + smem[1] + smem[2] + smem[3]) * (1.0f / BATCH);
}

extern "C" void kernel_launch(void* const* d_in, const int* in_sizes, int n_in,
                              void* d_out, int out_size, void* d_ws, size_t ws_size,
                              hipStream_t stream) {
    const float* features = (const float*)d_in[0];
    const int*   labels   = (const int*)d_in[1];
    const float* centers  = (const float*)d_in[2];
    float* out      = (float*)d_out;
    float* partials = (float*)d_ws;   // NPART floats, fully overwritten every call

    center_loss_partial<<<NBLK1, 256, 0, stream>>>(features, labels, centers, partials);
    center_loss_reduce<<<1, 256, 0, stream>>>(partials, out);
}

// Round 9
// 11.737 us; speedup vs baseline: 1.0637x; 1.0637x over previous
//
#include <hip/hip_runtime.h>

#define BATCH 8192
#define FEAT  512
#define NBLK1 (BATCH / 4)   // 2048 blocks x 4 waves = 8192 waves = 32/CU (full TLP; R2-proven)

__global__ __launch_bounds__(256) void center_loss_partial(
    const float* __restrict__ features,
    const int*   __restrict__ labels,
    const float* __restrict__ centers,
    float*       __restrict__ partials)   // one float per WAVE (8192) -- no LDS, no barrier
{
    const int lane  = threadIdx.x & 63;
    const int gwave = blockIdx.x * 4 + (threadIdx.x >> 6);  // == row
    const int row   = gwave;

    // wave-uniform label first; both feature loads overlap its latency
    const int lbl = labels[row];
    const float4* f = reinterpret_cast<const float4*>(features + (size_t)row * FEAT);
    const float4* c = reinterpret_cast<const float4*>(centers  + (size_t)lbl * FEAT);

    // 512 floats = 128 float4; 64 lanes -> 2 float4 each, 1 KB coalesced per load
    float4 f0 = f[lane];
    float4 f1 = f[lane + 64];
    float4 c0 = c[lane];
    float4 c1 = c[lane + 64];

    float acc, d;
    d = f0.x - c0.x; acc  = d * d;
    d = f0.y - c0.y; acc += d * d;
    d = f0.z - c0.z; acc += d * d;
    d = f0.w - c0.w; acc += d * d;
    d = f1.x - c1.x; acc += d * d;
    d = f1.y - c1.y; acc += d * d;
    d = f1.z - c1.z; acc += d * d;
    d = f1.w - c1.w; acc += d * d;

    #pragma unroll
    for (int off = 32; off > 0; off >>= 1)
        acc += __shfl_down(acc, off, 64);

    // wave retires immediately -- no __syncthreads, no LDS combine
    if (lane == 0) partials[gwave] = acc;
}

__global__ __launch_bounds__(256) void center_loss_reduce(
    const float* __restrict__ partials,
    float*       __restrict__ out)
{
    // 8192 floats = 2048 float4; 256 threads x 8 float4, all loads independent
    const float4* p = reinterpret_cast<const float4*>(partials);
    float4 q0 = p[threadIdx.x];
    float4 q1 = p[threadIdx.x + 256];
    float4 q2 = p[threadIdx.x + 512];
    float4 q3 = p[threadIdx.x + 768];
    float4 q4 = p[threadIdx.x + 1024];
    float4 q5 = p[threadIdx.x + 1280];
    float4 q6 = p[threadIdx.x + 1536];
    float4 q7 = p[threadIdx.x + 1792];
    float s = ((q0.x + q0.y) + (q0.z + q0.w)) + ((q1.x + q1.y) + (q1.z + q1.w))
            + ((q2.x + q2.y) + (q2.z + q2.w)) + ((q3.x + q3.y) + (q3.z + q3.w))
            + ((q4.x + q4.y) + (q4.z + q4.w)) + ((q5.x + q5.y) + (q5.z + q5.w))
            + ((q6.x + q6.y) + (q6.z + q6.w)) + ((q7.x + q7.y) + (q7.z + q7.w));

    #pragma unroll
    for (int off = 32; off > 0; off >>= 1)
        s += __shfl_down(s, off, 64);

    __shared__ float smem[4];
    const int lane = threadIdx.x & 63;
    const int wave = threadIdx.x >> 6;
    if (lane == 0) smem[wave] = s;
    __syncthreads();
    if (threadIdx.x == 0)
        out[0] = (smem[0] + smem[1] + smem[2] + smem[3]) * (1.0f / BATCH);
}

extern "C" void kernel_launch(void* const* d_in, const int* in_sizes, int n_in,
                              void* d_out, int out_size, void* d_ws, size_t ws_size,
                              hipStream_t stream) {
    const float* features = (const float*)d_in[0];
    const int*   labels   = (const int*)d_in[1];
    const float* centers  = (const float*)d_in[2];
    float* out      = (float*)d_out;
    float* partials = (float*)d_ws;   // 8192 floats, fully overwritten every call

    center_loss_partial<<<NBLK1, 256, 0, stream>>>(features, labels, centers, partials);
    center_loss_reduce<<<1, 256, 0, stream>>>(partials, out);
}

// Round 10
// 11.135 us; speedup vs baseline: 1.1212x; 1.0540x over previous
//
#include <hip/hip_runtime.h>

#define BATCH 8192
#define FEAT  512
#define NBLK1 (BATCH / 4)   // 2048 blocks, 4 waves/block, one wave per row (best measured: 10.9us)

__global__ __launch_bounds__(256) void center_loss_partial(
    const float* __restrict__ features,
    const int*   __restrict__ labels,
    const float* __restrict__ centers,
    float*       __restrict__ partials)
{
    const int lane = threadIdx.x & 63;
    const int wave = threadIdx.x >> 6;
    const int row  = blockIdx.x * 4 + wave;

    // label is wave-uniform; issue it first, feature loads overlap the latency
    const int lbl = labels[row];
    const float4* f = reinterpret_cast<const float4*>(features + (size_t)row * FEAT);
    const float4* c = reinterpret_cast<const float4*>(centers  + (size_t)lbl * FEAT);

    // 512 floats = 128 float4; 64 lanes -> 2 float4 each, 1 KB coalesced per load
    float4 f0 = f[lane];
    float4 f1 = f[lane + 64];
    float4 c0 = c[lane];
    float4 c1 = c[lane + 64];

    float acc, d;
    d = f0.x - c0.x; acc  = d * d;
    d = f0.y - c0.y; acc += d * d;
    d = f0.z - c0.z; acc += d * d;
    d = f0.w - c0.w; acc += d * d;
    d = f1.x - c1.x; acc += d * d;
    d = f1.y - c1.y; acc += d * d;
    d = f1.z - c1.z; acc += d * d;
    d = f1.w - c1.w; acc += d * d;

    #pragma unroll
    for (int off = 32; off > 0; off >>= 1)
        acc += __shfl_down(acc, off, 64);

    __shared__ float smem[4];
    if (lane == 0) smem[wave] = acc;
    __syncthreads();
    if (threadIdx.x == 0)
        partials[blockIdx.x] = smem[0] + smem[1] + smem[2] + smem[3];
}

__global__ __launch_bounds__(256) void center_loss_reduce(
    const float* __restrict__ partials,
    float*       __restrict__ out)
{
    // 2048 partials / 256 threads = 8 each (2x float4)
    const float4* p = reinterpret_cast<const float4*>(partials);
    float4 a = p[threadIdx.x];
    float4 b = p[threadIdx.x + 256];
    float s = (a.x + a.y + a.z + a.w) + (b.x + b.y + b.z + b.w);

    #pragma unroll
    for (int off = 32; off > 0; off >>= 1)
        s += __shfl_down(s, off, 64);

    __shared__ float smem[4];
    const int lane = threadIdx.x & 63;
    const int wave = threadIdx.x >> 6;
    if (lane == 0) smem[wave] = s;
    __syncthreads();
    if (threadIdx.x == 0)
        out[0] = (smem[0] + smem[1] + smem[2] + smem[3]) * (1.0f / BATCH);
}

extern "C" void kernel_launch(void* const* d_in, const int* in_sizes, int n_in,
                              void* d_out, int out_size, void* d_ws, size_t ws_size,
                              hipStream_t stream) {
    const float* features = (const float*)d_in[0];
    const int*   labels   = (const int*)d_in[1];
    const float* centers  = (const float*)d_in[2];
    float* out      = (float*)d_out;
    float* partials = (float*)d_ws;   // 2048 floats, written unconditionally each call

    center_loss_partial<<<NBLK1, 256, 0, stream>>>(features, labels, centers, partials);
    center_loss_reduce<<<1, 256, 0, stream>>>(partials, out);
}